// Round 2
// baseline (518.235 us; speedup 1.0000x reference)
//
#include <hip/hip_runtime.h>

// ---------------------------------------------------------------------------
// Qwen3 attention block: B=2 S=1024 H=4096 NH=32 NKV=8 D=128
// Round 6: gemm256_bt gets sched_barrier(0) window fences. Round-5 analysis:
// LDS-read and MFMA windows fully serialized (4387 cyc/K-tile = sum of both
// + overhead) because hipcc sinks ds_reads past the raw s_barrier builtin.
// Pins: {reads,stages} before barrier1, MFMAs after lgkmcnt(0), MFMA cluster
// within its phase. Sync structure (buffers/vmcnt/barriers) unchanged from
// the round-5 kernel that passed.
// ---------------------------------------------------------------------------

typedef float  f32x4   __attribute__((ext_vector_type(4)));
typedef float  f32x16  __attribute__((ext_vector_type(16)));
typedef __bf16 bf16x8  __attribute__((ext_vector_type(8)));
typedef unsigned short u16x8 __attribute__((ext_vector_type(8)));

__device__ __forceinline__ unsigned short f2b(float f) {
    union { float f; unsigned int u; } x;
    x.f = f;
    unsigned int u = x.u;
    unsigned int r = u + 0x7fffu + ((u >> 16) & 1u);   // RNE
    return (unsigned short)(r >> 16);
}

// async global->LDS, 16B per lane. LDS dst = wave-uniform base + lane*16.
__device__ __forceinline__ void async16(const unsigned short* g, unsigned short* l) {
    __builtin_amdgcn_global_load_lds(
        (const __attribute__((address_space(1))) void*)g,
        (__attribute__((address_space(3))) void*)l, 16, 0, 0);
}

// ---------------------------------------------------------------------------
// fp32 -> bf16 convert, all five regions in one launch. 8 elems/thread.
// ---------------------------------------------------------------------------
__global__ __launch_bounds__(256) void cvt_all(const float* __restrict__ hsrc,
                                               const float* __restrict__ wq,
                                               const float* __restrict__ wk,
                                               const float* __restrict__ wv,
                                               const float* __restrict__ wo,
                                               unsigned short* __restrict__ hidb,
                                               unsigned short* __restrict__ wqkvb,
                                               unsigned short* __restrict__ wob) {
    int i = blockIdx.x * 256 + threadIdx.x;
    if (i >= 6291456) return;
    const float* s; unsigned short* d; int j;
    if (i < 1048576)      { s = hsrc; d = hidb;             j = i; }
    else if (i < 3145728) { s = wq;   d = wqkvb;            j = i - 1048576; }
    else if (i < 3670016) { s = wk;   d = wqkvb + 16777216; j = i - 3145728; }
    else if (i < 4194304) { s = wv;   d = wqkvb + 20971520; j = i - 3670016; }
    else                  { s = wo;   d = wob;              j = i - 4194304; }
    const float4* s4 = (const float4*)s + (size_t)j * 2;
    float4 a = s4[0], b = s4[1];
    u16x8 o;
    o[0] = f2b(a.x); o[1] = f2b(a.y); o[2] = f2b(a.z); o[3] = f2b(a.w);
    o[4] = f2b(b.x); o[5] = f2b(b.y); o[6] = f2b(b.z); o[7] = f2b(b.w);
    *((u16x8*)d + j) = o;
}

// ---------------------------------------------------------------------------
// Deep-pipelined GEMM: C[M,N] fp32 = A[M,K]bf16 @ W[N,K]bf16^T.
// Tile 256x192, BK=64, 512 threads = 8 waves (2M x 4N), each wave 128x48
// via 8x3 grid of mfma_f32_16x16x32_bf16.
// LDS: A[3 bufs][256x64], B[2 bufs][192x64] = 144KB -> 1 block/CU.
// Per K-tile: 4 phases, each {reads+stage | SB | barrier | lgkm0 | SB | MFMA
// | SB | barrier}; one vmcnt(4) checkpoint at phase 3 leaves A(t+2) in
// flight; B(t+1)/A(t+1) proven landed at each tile boundary.
// ---------------------------------------------------------------------------
__global__ __launch_bounds__(512, 2) void gemm256_bt(const unsigned short* __restrict__ A,
                                                     const unsigned short* __restrict__ W,
                                                     float* __restrict__ C,
                                                     int K, int N) {
    __shared__ __align__(16) unsigned short Ab[3][256 * 64];
    __shared__ __align__(16) unsigned short Bb[2][192 * 64];

    const int tid  = threadIdx.x;
    const int wave = tid >> 6, lane = tid & 63;
    const int wm   = wave >> 2, wn = wave & 3;
    const int l15  = lane & 15, h = lane >> 4;
    const int cx0  = (h ^ (l15 & 7)) << 3;            // frag read chunk, ks=0 (shorts)
    const int cx1  = cx0 ^ 32;                        // ks=1
    const int stgrow = wave * 8 + (lane >> 3);        // row within 64-row sweep
    const int stgcol = ((lane & 7) ^ (lane >> 3)) << 3; // pre-swizzled global chunk
    const int aRow0 = blockIdx.y * 256;
    const int bRow0 = blockIdx.x * 192;
    const int NT = K >> 6;

#define STAGE_A(t, s, bi) async16(A + (size_t)(aRow0 + (s)*64 + stgrow) * K + (t)*64 + stgcol, \
                                  &Ab[bi][(s)*4096 + wave*512])
#define STAGE_B(t, s, bi) async16(W + (size_t)(bRow0 + (s)*64 + stgrow) * K + (t)*64 + stgcol, \
                                  &Bb[bi][(s)*4096 + wave*512])
#define LOAD_AQ(q) do { \
    _Pragma("unroll") \
    for (int mi = 0; mi < 2; mi++) { \
        const unsigned short* ap = Ab_ + (wm * 128 + (q) * 32 + mi * 16 + l15) * 64; \
        af[mi][0] = *(const bf16x8*)(ap + cx0); \
        af[mi][1] = *(const bf16x8*)(ap + cx1); \
    } } while (0)
#define MFMA_Q(q) do { \
    _Pragma("unroll") \
    for (int mi = 0; mi < 2; mi++) \
    _Pragma("unroll") \
    for (int nf = 0; nf < 3; nf++) { \
        acc[(q)*2+mi][nf] = __builtin_amdgcn_mfma_f32_16x16x32_bf16(af[mi][0], bfr[nf][0], acc[(q)*2+mi][nf], 0, 0, 0); \
        acc[(q)*2+mi][nf] = __builtin_amdgcn_mfma_f32_16x16x32_bf16(af[mi][1], bfr[nf][1], acc[(q)*2+mi][nf], 0, 0, 0); \
    } } while (0)
#define SB()      __builtin_amdgcn_sched_barrier(0)
#define BARRIER() __builtin_amdgcn_s_barrier()
#define LGKM0()   asm volatile("s_waitcnt lgkmcnt(0)" ::: "memory")
// phase skeleton: [reads+stages already issued] SB barrier LGKM0 SB MFMA SB barrier
#define PHASE_SYNC_IN()  do { SB(); BARRIER(); LGKM0(); SB(); } while (0)
#define PHASE_SYNC_OUT() do { SB(); BARRIER(); } while (0)

    f32x4 acc[8][3] = {};

    // prologue: B(0) -> Bb0, A(0) -> Ab0, A(1) -> Ab1; leave A(1) in flight
    STAGE_B(0, 0, 0); STAGE_B(0, 1, 0); STAGE_B(0, 2, 0);
    STAGE_A(0, 0, 0); STAGE_A(0, 1, 0); STAGE_A(0, 2, 0); STAGE_A(0, 3, 0);
    STAGE_A(1, 0, 1); STAGE_A(1, 1, 1); STAGE_A(1, 2, 1); STAGE_A(1, 3, 1);
    asm volatile("s_waitcnt vmcnt(4)" ::: "memory");
    SB(); BARRIER(); SB();

    for (int t = 0; t < NT; ++t) {
        const unsigned short* Ab_ = Ab[t % 3];
        const unsigned short* Bb_ = Bb[t & 1];
        const int rb1 = (t & 1) ^ 1, ra2 = (t + 2) % 3;
        const bool sb = (t + 1 < NT), sa = (t + 2 < NT);
        bf16x8 af[2][2], bfr[3][2];

        // ---- phase 0: B frags (whole tile) + A quad0
        #pragma unroll
        for (int nf = 0; nf < 3; nf++) {
            const unsigned short* bp = Bb_ + (wn * 48 + nf * 16 + l15) * 64;
            bfr[nf][0] = *(const bf16x8*)(bp + cx0);
            bfr[nf][1] = *(const bf16x8*)(bp + cx1);
        }
        LOAD_AQ(0);
        if (sb) { STAGE_B(t + 1, 0, rb1); STAGE_B(t + 1, 1, rb1); }
        PHASE_SYNC_IN();
        __builtin_amdgcn_s_setprio(1); MFMA_Q(0); __builtin_amdgcn_s_setprio(0);
        PHASE_SYNC_OUT();

        // ---- phase 1
        LOAD_AQ(1);
        if (sb) STAGE_B(t + 1, 2, rb1);
        if (sa) STAGE_A(t + 2, 0, ra2);
        PHASE_SYNC_IN();
        __builtin_amdgcn_s_setprio(1); MFMA_Q(1); __builtin_amdgcn_s_setprio(0);
        PHASE_SYNC_OUT();

        // ---- phase 2
        LOAD_AQ(2);
        if (sa) { STAGE_A(t + 2, 1, ra2); STAGE_A(t + 2, 2, ra2); }
        PHASE_SYNC_IN();
        __builtin_amdgcn_s_setprio(1); MFMA_Q(2); __builtin_amdgcn_s_setprio(0);
        PHASE_SYNC_OUT();

        // ---- phase 3 + checkpoint
        LOAD_AQ(3);
        if (sa) STAGE_A(t + 2, 3, ra2);
        if (sa) asm volatile("s_waitcnt vmcnt(4)" ::: "memory");
        else    asm volatile("s_waitcnt vmcnt(0)" ::: "memory");
        PHASE_SYNC_IN();
        __builtin_amdgcn_s_setprio(1); MFMA_Q(3); __builtin_amdgcn_s_setprio(0);
        PHASE_SYNC_OUT();
    }

    // epilogue: C/D 16x16 frag layout col=l&15, row=(l>>4)*4+r
    #pragma unroll
    for (int mf = 0; mf < 8; mf++)
        #pragma unroll
        for (int nf = 0; nf < 3; nf++)
            #pragma unroll
            for (int r = 0; r < 4; r++) {
                int row = aRow0 + wm * 128 + mf * 16 + h * 4 + r;
                int col = bRow0 + wn * 48 + nf * 16 + l15;
                C[(size_t)row * N + col] = acc[mf][nf][r];
            }
#undef STAGE_A
#undef STAGE_B
#undef LOAD_AQ
#undef MFMA_Q
#undef SB
#undef BARRIER
#undef LGKM0
#undef PHASE_SYNC_IN
#undef PHASE_SYNC_OUT
}

// ---------------------------------------------------------------------------
// GEMM: C[M,N] fp32 = A[M,K]bf16 @ W[N,K]bf16^T. 128x128 tile, BK=64.
// (kept for the output projection: N=4096 not divisible by 192)
// ---------------------------------------------------------------------------
__global__ __launch_bounds__(256) void gemm_bt_bf16(const unsigned short* __restrict__ A,
                                                    const unsigned short* __restrict__ W,
                                                    float* __restrict__ C,
                                                    int K, int N) {
    __shared__ __align__(16) unsigned short As[128 * 64];
    __shared__ __align__(16) unsigned short Bs[128 * 64];

    const int tid  = threadIdx.x;
    const int wave = tid >> 6, lane = tid & 63;
    const int wm   = wave >> 1, wn = wave & 1;
    const int l31  = lane & 31, lh = lane >> 5;
    const int arow = blockIdx.y * 128, brow = blockIdx.x * 128;

    int rr[4], gc[4], slot[4];
    #pragma unroll
    for (int it = 0; it < 4; it++) {
        slot[it] = it * 4 + wave;
        int ci = slot[it] * 64 + lane;
        rr[it] = ci >> 3;
        int c  = ci & 7;
        gc[it] = c ^ (rr[it] & 7);
    }

    f32x16 acc[2][2] = {};

    for (int k0 = 0; k0 < K; k0 += 64) {
        #pragma unroll
        for (int it = 0; it < 4; it++) {
            async16(A + (size_t)(arow + rr[it]) * K + k0 + gc[it] * 8, &As[slot[it] * 512]);
            async16(W + (size_t)(brow + rr[it]) * K + k0 + gc[it] * 8, &Bs[slot[it] * 512]);
        }
        __syncthreads();

        bf16x8 af[4][2], bfr[4][2];
        #pragma unroll
        for (int ks = 0; ks < 4; ks++) {
            #pragma unroll
            for (int i = 0; i < 2; i++) {
                int rowa = wm * 64 + i * 32 + l31;
                int ch   = (ks * 2 + lh) ^ (rowa & 7);
                af[ks][i]  = *(const bf16x8*)&As[rowa * 64 + ch * 8];
                int rowb = wn * 64 + i * 32 + l31;
                int chb  = (ks * 2 + lh) ^ (rowb & 7);
                bfr[ks][i] = *(const bf16x8*)&Bs[rowb * 64 + chb * 8];
            }
        }
        #pragma unroll
        for (int ks = 0; ks < 4; ks++)
            #pragma unroll
            for (int i = 0; i < 2; i++)
                #pragma unroll
                for (int j = 0; j < 2; j++)
                    acc[i][j] = __builtin_amdgcn_mfma_f32_32x32x16_bf16(af[ks][i], bfr[ks][j], acc[i][j], 0, 0, 0);
        __syncthreads();
    }

    #pragma unroll
    for (int i = 0; i < 2; i++)
        #pragma unroll
        for (int j = 0; j < 2; j++)
            #pragma unroll
            for (int r = 0; r < 16; r++) {
                int row = arow + wm * 64 + i * 32 + lh * 4 + (r & 3) + 8 * (r >> 2);
                int col = brow + wn * 64 + j * 32 + l31;
                C[(size_t)row * N + col] = acc[i][j][r];
            }
}

// ---------------------------------------------------------------------------
// RMSNorm + RoPE: fp32 [rows][rstride] (col-offset pre-applied) -> bf16
// [B][nh][S][128]. One wave per (row, head).
// ---------------------------------------------------------------------------
__global__ __launch_bounds__(256) void norm_rope(const float* __restrict__ X, int rstride,
                                                 const float* __restrict__ cosp,
                                                 const float* __restrict__ sinp,
                                                 const float* __restrict__ w,
                                                 unsigned short* __restrict__ Y, int nh) {
    const int wid  = blockIdx.x * 4 + (threadIdx.x >> 6);
    const int lane = threadIdx.x & 63;
    const int row  = wid / nh;
    const int h    = wid - row * nh;

    const float* xp = X + (size_t)row * rstride + h * 128;
    float x0 = xp[lane], x1 = xp[lane + 64];
    float ss = x0 * x0 + x1 * x1;
    #pragma unroll
    for (int off = 32; off; off >>= 1) ss += __shfl_xor(ss, off, 64);
    float r = rsqrtf(ss * (1.0f / 128.0f) + 1e-6f);
    float n0 = x0 * r * w[lane];
    float n1 = x1 * r * w[lane + 64];
    const float* cp = cosp + (size_t)row * 128;
    const float* sp = sinp + (size_t)row * 128;
    float y0 = n0 * cp[lane]      - n1 * sp[lane];
    float y1 = n1 * cp[lane + 64] + n0 * sp[lane + 64];
    const int b = row >> 10, s = row & 1023;
    unsigned short* yp = Y + (((size_t)(b * nh + h)) * 1024 + s) * 128;
    yp[lane]      = f2b(y0);
    yp[lane + 64] = f2b(y1);
}

// ---------------------------------------------------------------------------
// V transpose via LDS: fp32 V-region rows [b*1024+s][6144] (pointer
// pre-offset to col 5120) -> bf16 Vt[b][h][128][1024]. 64x64 tiles.
// ---------------------------------------------------------------------------
__global__ __launch_bounds__(256) void v_trans(const float* __restrict__ V,
                                               unsigned short* __restrict__ Vt) {
    __shared__ float T[64][65];
    const int tid = threadIdx.x;
    const int st = blockIdx.x >> 1, dt = blockIdx.x & 1;
    const int bh = blockIdx.y, b = bh >> 3, h = bh & 7;

    const int sl = tid >> 2, c0 = (tid & 3) * 16;
    const float* src = V + (size_t)(b * 1024 + st * 64 + sl) * 6144 + h * 128 + dt * 64 + c0;
    #pragma unroll
    for (int j = 0; j < 4; j++) {
        float4 v = *(const float4*)(src + j * 4);
        *(float4*)&T[sl][c0 + j * 4] = v;
    }
    __syncthreads();

    const int dgrp = tid >> 6, sl2 = tid & 63;
    unsigned short* dst = Vt + (size_t)bh * 131072 + st * 64 + sl2;
    #pragma unroll
    for (int jd = 0; jd < 16; jd++) {
        int dl = dgrp * 16 + jd;
        dst[(size_t)(dt * 64 + dl) * 1024] = f2b(T[sl2][dl]);
    }
}

// ---------------------------------------------------------------------------
// Flash attention (causal, GQA 4:1). Block = 64 Q rows (4 waves x 16 rows),
// processes q-tiles {qt, 15-qt} -> 9 k-tiles per block (balanced).
// ---------------------------------------------------------------------------
__global__ __launch_bounds__(256) void attn(const unsigned short* __restrict__ Qb,
                                            const unsigned short* __restrict__ Kb,
                                            const unsigned short* __restrict__ Vt,
                                            unsigned short* __restrict__ Ob) {
    __shared__ __align__(16) unsigned short Klds[128 * 128];
    __shared__ __align__(16) unsigned short Plds[4][16][136];

    const int tid  = threadIdx.x;
    const int w    = tid >> 6, lane = tid & 63;
    const int quad = lane >> 4, l15 = lane & 15;
    const int h = blockIdx.y, b = blockIdx.z, kvh = h >> 2;

    const unsigned short* Qp = Qb + ((size_t)(b * 32 + h))   * 131072;
    const unsigned short* Kp = Kb + ((size_t)(b * 8 + kvh))  * 131072;
    const unsigned short* Vp = Vt + ((size_t)(b * 8 + kvh))  * 131072;
    const float c2 = (float)(0.08838834764831845 * 1.4426950408889634); // D^-.5 * log2(e)

    for (int half = 0; half < 2; half++) {
        const int qt = half ? (15 - (int)blockIdx.x) : (int)blockIdx.x;
        const int q0 = qt * 64;
        const int qrow = q0 + w * 16 + l15;

        bf16x8 qf[4];
        #pragma unroll
        for (int ks = 0; ks < 4; ks++)
            qf[ks] = *(const bf16x8*)(Qp + (size_t)qrow * 128 + ks * 32 + quad * 8);

        float m_i[4], l_i[4];
        #pragma unroll
        for (int r = 0; r < 4; r++) { m_i[r] = -1e30f; l_i[r] = 0.0f; }
        f32x4 o[8] = {};

        const int ntiles = (qt >> 1) + 1;
        const int nfull  = (qt * 64 + 1) >> 7;   // tiles [0,nfull) need no mask

        for (int kt = 0; kt < ntiles; kt++) {
            __syncthreads();   // Klds readers of previous tile are done
            #pragma unroll
            for (int it = 0; it < 8; it++) {
                int slot = it * 4 + w;
                int ci = slot * 64 + lane;
                int r = ci >> 4, c = ci & 15;
                int g = (c & 8) | ((c ^ r) & 7);
                async16(Kp + (size_t)(kt * 128 + r) * 128 + g * 8, &Klds[slot * 512]);
            }
            __syncthreads();

            // S = Q @ K^T
            f32x4 sacc[8] = {};
            __builtin_amdgcn_s_setprio(1);
            #pragma unroll
            for (int ks = 0; ks < 4; ks++) {
                #pragma unroll
                for (int tn = 0; tn < 8; tn++) {
                    int row = tn * 16 + l15;
                    int ch  = ks * 4 + quad;
                    int chs = (ch & 8) | ((ch ^ row) & 7);
                    bf16x8 kf = *(const bf16x8*)&Klds[row * 128 + chs * 8];
                    sacc[tn] = __builtin_amdgcn_mfma_f32_16x16x32_bf16(qf[ks], kf, sacc[tn], 0, 0, 0);
                }
            }
            __builtin_amdgcn_s_setprio(0);

            const bool masked = (kt >= nfull);
            #pragma unroll
            for (int r = 0; r < 4; r++) {
                float sv[8];
                float rmax = -1e30f;
                if (masked) {
                    const int qg = q0 + w * 16 + quad * 4 + r;
                    #pragma unroll
                    for (int tn = 0; tn < 8; tn++) {
                        float v = sacc[tn][r];
                        int kg = kt * 128 + tn * 16 + l15;
                        if (kg > qg) v = -1e30f;
                        sv[tn] = v;
                        rmax = fmaxf(rmax, v);
                    }
                } else {
                    #pragma unroll
                    for (int tn = 0; tn < 8; tn++) {
                        sv[tn] = sacc[tn][r];
                        rmax = fmaxf(rmax, sv[tn]);
                    }
                }
                #pragma unroll
                for (int off = 8; off; off >>= 1) rmax = fmaxf(rmax, __shfl_xor(rmax, off, 16));
                float mnew  = fmaxf(m_i[r], rmax);
                float alpha = __builtin_amdgcn_exp2f((m_i[r] - mnew) * c2);
                float rsum  = 0.0f;
                #pragma unroll
                for (int tn = 0; tn < 8; tn++) {
                    float p = __builtin_amdgcn_exp2f((sv[tn] - mnew) * c2);
                    sv[tn] = p;
                    rsum += p;
                }
                #pragma unroll
                for (int off = 8; off; off >>= 1) rsum += __shfl_xor(rsum, off, 16);
                m_i[r] = mnew;
                l_i[r] = l_i[r] * alpha + rsum;
                #pragma unroll
                for (int td = 0; td < 8; td++) o[td][r] *= alpha;
                #pragma unroll
                for (int tn = 0; tn < 8; tn++)
                    Plds[w][quad * 4 + r][tn * 16 + l15] = f2b(sv[tn]);
            }

            // O += P @ V
            __builtin_amdgcn_s_setprio(1);
            #pragma unroll
            for (int ks = 0; ks < 4; ks++) {
                bf16x8 pf = *(const bf16x8*)&Plds[w][l15][ks * 32 + quad * 8];
                #pragma unroll
                for (int td = 0; td < 8; td++) {
                    bf16x8 vf = *(const bf16x8*)(Vp + (size_t)(td * 16 + l15) * 1024 + kt * 128 + ks * 32 + quad * 8);
                    o[td] = __builtin_amdgcn_mfma_f32_16x16x32_bf16(pf, vf, o[td], 0, 0, 0);
                }
            }
            __builtin_amdgcn_s_setprio(0);
        }

        #pragma unroll
        for (int r = 0; r < 4; r++) {
            float inv = 1.0f / l_i[r];
            const int qg = q0 + w * 16 + quad * 4 + r;
            unsigned short* op = Ob + ((size_t)(b * 1024 + qg)) * 4096 + h * 128;
            #pragma unroll
            for (int td = 0; td < 8; td++)
                op[td * 16 + l15] = f2b(o[td][r] * inv);
        }
    }
}

// ---------------------------------------------------------------------------
extern "C" void kernel_launch(void* const* d_in, const int* in_sizes, int n_in,
                              void* d_out, int out_size, void* d_ws, size_t ws_size,
                              hipStream_t stream) {
    const float* hid  = (const float*)d_in[0];
    const float* cosp = (const float*)d_in[1];
    const float* sinp = (const float*)d_in[2];
    const float* Wq   = (const float*)d_in[3];
    const float* Wk   = (const float*)d_in[4];
    const float* Wv   = (const float*)d_in[5];
    const float* Wo   = (const float*)d_in[6];
    const float* qw   = (const float*)d_in[7];
    const float* kw   = (const float*)d_in[8];
    float* out = (float*)d_out;

    // workspace carve (~176 MB)
    char* ws = (char*)d_ws;
    float* QKVf = (float*)ws;                               // [2048][6144] fp32 (50.3MB)
    unsigned short* Ob = (unsigned short*)ws;               // alias: QKVf dead before attn
    size_t off = (size_t)2048 * 6144 * 4;
    unsigned short* hidb  = (unsigned short*)(ws + off); off += (size_t)2048 * 4096 * 2;
    unsigned short* Wqkvb = (unsigned short*)(ws + off); off += (size_t)6144 * 4096 * 2;
    unsigned short* Wob   = (unsigned short*)(ws + off); off += (size_t)4096 * 4096 * 2;
    unsigned short* Qb    = (unsigned short*)(ws + off); off += (size_t)2048 * 4096 * 2;
    unsigned short* Kb    = (unsigned short*)(ws + off); off += (size_t)2048 * 1024 * 2;
    unsigned short* Vt    = (unsigned short*)(ws + off);

    dim3 blk(256);
    // fp32 -> bf16 converts (single launch)
    cvt_all<<<24576, blk, 0, stream>>>(hid, Wq, Wk, Wv, Wo, hidb, Wqkvb, Wob);
    // fused QKV projection: [2048][6144] = hidb @ Wqkvb^T (256x192 tiles)
    gemm256_bt<<<dim3(32, 8), dim3(512), 0, stream>>>(hidb, Wqkvb, QKVf, 4096, 6144);
    // norm + rope + layout
    norm_rope<<<16384, blk, 0, stream>>>(QKVf,        6144, cosp, sinp, qw, Qb, 32);
    norm_rope<<<4096,  blk, 0, stream>>>(QKVf + 4096, 6144, cosp, sinp, kw, Kb, 8);
    v_trans<<<dim3(32, 16), blk, 0, stream>>>(QKVf + 5120, Vt);
    // attention
    attn<<<dim3(8, 32, 2), blk, 0, stream>>>(Qb, Kb, Vt, Ob);
    // output projection
    gemm_bt_bf16<<<dim3(32, 16), blk, 0, stream>>>(Ob, Wob, out, 4096, 4096);
}

// Round 3
// 513.428 us; speedup vs baseline: 1.0094x; 1.0094x over previous
//
#include <hip/hip_runtime.h>

// ---------------------------------------------------------------------------
// Qwen3 attention block: B=2 S=1024 H=4096 NH=32 NKV=8 D=128
// Round 7: gemm256_bt K-loop gets the "derived waits" port: one-phase-ahead
// register prefetch + counted lgkmcnt (never 0 in steady state). Phase p
// issues ds_reads for quadrant p+1; waits lgkmcnt(4) (proves prev phase's
// reads, leaves new ones in flight under the MFMA). vmcnt checkpoint moved
// to phase 2 (vmcnt(3)) so the tile-boundary reads at phase 3 are cross-wave
// safe after p2's barrier. Steady-state: no lgkm/vm full drains.
// Workspace 176->148MB (Qb aliases hidb; Kb/Vt alias Wqkvb).
// ---------------------------------------------------------------------------

typedef float  f32x4   __attribute__((ext_vector_type(4)));
typedef float  f32x16  __attribute__((ext_vector_type(16)));
typedef __bf16 bf16x8  __attribute__((ext_vector_type(8)));
typedef unsigned short u16x8 __attribute__((ext_vector_type(8)));

__device__ __forceinline__ unsigned short f2b(float f) {
    union { float f; unsigned int u; } x;
    x.f = f;
    unsigned int u = x.u;
    unsigned int r = u + 0x7fffu + ((u >> 16) & 1u);   // RNE
    return (unsigned short)(r >> 16);
}

// async global->LDS, 16B per lane. LDS dst = wave-uniform base + lane*16.
__device__ __forceinline__ void async16(const unsigned short* g, unsigned short* l) {
    __builtin_amdgcn_global_load_lds(
        (const __attribute__((address_space(1))) void*)g,
        (__attribute__((address_space(3))) void*)l, 16, 0, 0);
}

// ---------------------------------------------------------------------------
// fp32 -> bf16 convert, all five regions in one launch. 8 elems/thread.
// ---------------------------------------------------------------------------
__global__ __launch_bounds__(256) void cvt_all(const float* __restrict__ hsrc,
                                               const float* __restrict__ wq,
                                               const float* __restrict__ wk,
                                               const float* __restrict__ wv,
                                               const float* __restrict__ wo,
                                               unsigned short* __restrict__ hidb,
                                               unsigned short* __restrict__ wqkvb,
                                               unsigned short* __restrict__ wob) {
    int i = blockIdx.x * 256 + threadIdx.x;
    if (i >= 6291456) return;
    const float* s; unsigned short* d; int j;
    if (i < 1048576)      { s = hsrc; d = hidb;             j = i; }
    else if (i < 3145728) { s = wq;   d = wqkvb;            j = i - 1048576; }
    else if (i < 3670016) { s = wk;   d = wqkvb + 16777216; j = i - 3145728; }
    else if (i < 4194304) { s = wv;   d = wqkvb + 20971520; j = i - 3670016; }
    else                  { s = wo;   d = wob;              j = i - 4194304; }
    const float4* s4 = (const float4*)s + (size_t)j * 2;
    float4 a = s4[0], b = s4[1];
    u16x8 o;
    o[0] = f2b(a.x); o[1] = f2b(a.y); o[2] = f2b(a.z); o[3] = f2b(a.w);
    o[4] = f2b(b.x); o[5] = f2b(b.y); o[6] = f2b(b.z); o[7] = f2b(b.w);
    *((u16x8*)d + j) = o;
}

// ---------------------------------------------------------------------------
// Deep-pipelined GEMM: C[M,N] fp32 = A[M,K]bf16 @ W[N,K]bf16^T.
// Tile 256x192, BK=64, 512 threads = 8 waves (2M x 4N), each wave 128x48
// via 8x3 grid of mfma_f32_16x16x32_bf16. Grid 32x8 = 256 blocks = 1/CU.
// LDS: A[3 bufs][256x64], B[2 bufs][192x64] = 144KB.
// Per K-tile t (4 phases). Register pipeline: A-quads rA..rD, B cur/next.
//  p0: rd q1->rB; stage B(t+1)s0,s1;          bar; lgkm(4);  MFMA q0(rA,BC); bar
//  p1: rd q2->rC; stage Bs2, A(t+2)s0;        bar; lgkm(4);  MFMA q1(rB,BC); bar
//  p2: rd q3->rD; stage As1,s2; vmcnt(3);     bar; lgkm(4);  MFMA q2(rC,BC); bar
//  p3: rd q0'->rA, B'->BN (from t+1 bufs, proven by p2 vmcnt+bar); stage As3;
//                                             bar; lgkm(10); MFMA q3(rD,BC); bar
// In-flight vmem {4,6,8,10->3,4}; lgkm never drained to 0 in steady state.
// ---------------------------------------------------------------------------
__global__ __launch_bounds__(512, 2) void gemm256_bt(const unsigned short* __restrict__ A,
                                                     const unsigned short* __restrict__ W,
                                                     float* __restrict__ C,
                                                     int K, int N) {
    __shared__ __align__(16) unsigned short Ab[3][256 * 64];
    __shared__ __align__(16) unsigned short Bb[2][192 * 64];

    const int tid  = threadIdx.x;
    const int wave = tid >> 6, lane = tid & 63;
    const int wm   = wave >> 2, wn = wave & 3;
    const int l15  = lane & 15, h = lane >> 4;
    const int cx0  = (h ^ (l15 & 7)) << 3;              // frag read chunk (shorts)
    const int cx1  = cx0 ^ 32;                          // k + 32
    const int stgrow = wave * 8 + (lane >> 3);          // row within 64-row sweep
    const int stgcol = ((lane & 7) ^ (lane >> 3)) << 3; // pre-swizzled global chunk
    const int aRow0 = blockIdx.y * 256;
    const int bRow0 = blockIdx.x * 192;
    const int NT = K >> 6;

#define STAGE_A(t, s, bi) async16(A + (size_t)(aRow0 + (s)*64 + stgrow) * K + (t)*64 + stgcol, \
                                  &Ab[bi][(s)*4096 + wave*512])
#define STAGE_B(t, s, bi) async16(W + (size_t)(bRow0 + (s)*64 + stgrow) * K + (t)*64 + stgcol, \
                                  &Bb[bi][(s)*4096 + wave*512])
#define RD_AQ(dst, buf, q) do { \
    _Pragma("unroll") \
    for (int mi = 0; mi < 2; mi++) { \
        const unsigned short* ap_ = (buf) + (wm * 128 + (q) * 32 + mi * 16 + l15) * 64; \
        dst[mi][0] = *(const bf16x8*)(ap_ + cx0); \
        dst[mi][1] = *(const bf16x8*)(ap_ + cx1); \
    } } while (0)
#define RD_B(dst, buf) do { \
    _Pragma("unroll") \
    for (int nf = 0; nf < 3; nf++) { \
        const unsigned short* bp_ = (buf) + (wn * 48 + nf * 16 + l15) * 64; \
        dst[nf][0] = *(const bf16x8*)(bp_ + cx0); \
        dst[nf][1] = *(const bf16x8*)(bp_ + cx1); \
    } } while (0)
#define MFMA_Q(q, AR, BR) do { \
    _Pragma("unroll") \
    for (int mi = 0; mi < 2; mi++) \
    _Pragma("unroll") \
    for (int nf = 0; nf < 3; nf++) { \
        acc[(q)*2+mi][nf] = __builtin_amdgcn_mfma_f32_16x16x32_bf16(AR[mi][0], BR[nf][0], acc[(q)*2+mi][nf], 0, 0, 0); \
        acc[(q)*2+mi][nf] = __builtin_amdgcn_mfma_f32_16x16x32_bf16(AR[mi][1], BR[nf][1], acc[(q)*2+mi][nf], 0, 0, 0); \
    } } while (0)
#define SB()      __builtin_amdgcn_sched_barrier(0)
#define BARRIER() __builtin_amdgcn_s_barrier()
#define PRIO1()   __builtin_amdgcn_s_setprio(1)
#define PRIO0()   __builtin_amdgcn_s_setprio(0)
#define LGKM(n)   asm volatile("s_waitcnt lgkmcnt(" #n ")" ::: "memory")

#define TILE(T, BC, BN_) do { \
    const int t_ = (T); \
    const unsigned short* Ab_  = Ab[t_ % 3]; \
    const unsigned short* AbN_ = Ab[(t_ + 1) % 3]; \
    const unsigned short* BbN_ = Bb[(t_ + 1) & 1]; \
    const int rb1 = (t_ & 1) ^ 1, ra2 = (t_ + 2) % 3; \
    const bool sb = (t_ + 1 < NT), sa = (t_ + 2 < NT); \
    /* ---- p0 */ \
    RD_AQ(rB, Ab_, 1); \
    if (sb) { STAGE_B(t_ + 1, 0, rb1); STAGE_B(t_ + 1, 1, rb1); } \
    SB(); BARRIER(); LGKM(4); SB(); \
    PRIO1(); MFMA_Q(0, rA, BC); PRIO0(); SB(); BARRIER(); \
    /* ---- p1 */ \
    RD_AQ(rC, Ab_, 2); \
    if (sb) STAGE_B(t_ + 1, 2, rb1); \
    if (sa) STAGE_A(t_ + 2, 0, ra2); \
    SB(); BARRIER(); LGKM(4); SB(); \
    PRIO1(); MFMA_Q(1, rB, BC); PRIO0(); SB(); BARRIER(); \
    /* ---- p2 (+vm checkpoint: proves A(t+1)+B(t+1) landed) */ \
    RD_AQ(rD, Ab_, 3); \
    if (sa) { STAGE_A(t_ + 2, 1, ra2); STAGE_A(t_ + 2, 2, ra2); \
              asm volatile("s_waitcnt vmcnt(3)" ::: "memory"); } \
    else    { asm volatile("s_waitcnt vmcnt(0)" ::: "memory"); } \
    SB(); BARRIER(); LGKM(4); SB(); \
    PRIO1(); MFMA_Q(2, rC, BC); PRIO0(); SB(); BARRIER(); \
    /* ---- p3 (boundary reads from t+1 buffers; safe after p2 bar) */ \
    if (sb) { RD_AQ(rA, AbN_, 0); RD_B(BN_, BbN_); } \
    if (sa) STAGE_A(t_ + 2, 3, ra2); \
    SB(); BARRIER(); \
    if (sb) { LGKM(10); } else { LGKM(0); } \
    SB(); \
    PRIO1(); MFMA_Q(3, rD, BC); PRIO0(); SB(); BARRIER(); \
} while (0)

    f32x4 acc[8][3] = {};
    bf16x8 rA[2][2], rB[2][2], rC[2][2], rD[2][2];
    bf16x8 bc[3][2], bn[3][2];

    // prologue: B(0)->Bb0, A(0)->Ab0, A(1)->Ab1; leave A(1) in flight
    STAGE_B(0, 0, 0); STAGE_B(0, 1, 0); STAGE_B(0, 2, 0);
    STAGE_A(0, 0, 0); STAGE_A(0, 1, 0); STAGE_A(0, 2, 0); STAGE_A(0, 3, 0);
    STAGE_A(1, 0, 1); STAGE_A(1, 1, 1); STAGE_A(1, 2, 1); STAGE_A(1, 3, 1);
    asm volatile("s_waitcnt vmcnt(4)" ::: "memory");
    SB(); BARRIER(); SB();
    // pre-read tile 0: q0 + B  (10 reads outstanding entering the loop)
    RD_B(bc, Bb[0]);
    RD_AQ(rA, Ab[0], 0);
    SB();

    for (int t = 0; t < NT; t += 2) {
        TILE(t,     bc, bn);
        TILE(t + 1, bn, bc);
    }

    // epilogue: C/D 16x16 frag layout col=l&15, row=(l>>4)*4+r
    #pragma unroll
    for (int mf = 0; mf < 8; mf++)
        #pragma unroll
        for (int nf = 0; nf < 3; nf++)
            #pragma unroll
            for (int r = 0; r < 4; r++) {
                int row = aRow0 + wm * 128 + mf * 16 + h * 4 + r;
                int col = bRow0 + wn * 48 + nf * 16 + l15;
                C[(size_t)row * N + col] = acc[mf][nf][r];
            }
#undef STAGE_A
#undef STAGE_B
#undef RD_AQ
#undef RD_B
#undef MFMA_Q
#undef SB
#undef BARRIER
#undef PRIO1
#undef PRIO0
#undef LGKM
#undef TILE
}

// ---------------------------------------------------------------------------
// GEMM: C[M,N] fp32 = A[M,K]bf16 @ W[N,K]bf16^T. 128x128 tile, BK=64.
// (kept for the output projection: N=4096 not divisible by 192)
// ---------------------------------------------------------------------------
__global__ __launch_bounds__(256) void gemm_bt_bf16(const unsigned short* __restrict__ A,
                                                    const unsigned short* __restrict__ W,
                                                    float* __restrict__ C,
                                                    int K, int N) {
    __shared__ __align__(16) unsigned short As[128 * 64];
    __shared__ __align__(16) unsigned short Bs[128 * 64];

    const int tid  = threadIdx.x;
    const int wave = tid >> 6, lane = tid & 63;
    const int wm   = wave >> 1, wn = wave & 1;
    const int l31  = lane & 31, lh = lane >> 5;
    const int arow = blockIdx.y * 128, brow = blockIdx.x * 128;

    int rr[4], gc[4], slot[4];
    #pragma unroll
    for (int it = 0; it < 4; it++) {
        slot[it] = it * 4 + wave;
        int ci = slot[it] * 64 + lane;
        rr[it] = ci >> 3;
        int c  = ci & 7;
        gc[it] = c ^ (rr[it] & 7);
    }

    f32x16 acc[2][2] = {};

    for (int k0 = 0; k0 < K; k0 += 64) {
        #pragma unroll
        for (int it = 0; it < 4; it++) {
            async16(A + (size_t)(arow + rr[it]) * K + k0 + gc[it] * 8, &As[slot[it] * 512]);
            async16(W + (size_t)(brow + rr[it]) * K + k0 + gc[it] * 8, &Bs[slot[it] * 512]);
        }
        __syncthreads();

        bf16x8 af[4][2], bfr[4][2];
        #pragma unroll
        for (int ks = 0; ks < 4; ks++) {
            #pragma unroll
            for (int i = 0; i < 2; i++) {
                int rowa = wm * 64 + i * 32 + l31;
                int ch   = (ks * 2 + lh) ^ (rowa & 7);
                af[ks][i]  = *(const bf16x8*)&As[rowa * 64 + ch * 8];
                int rowb = wn * 64 + i * 32 + l31;
                int chb  = (ks * 2 + lh) ^ (rowb & 7);
                bfr[ks][i] = *(const bf16x8*)&Bs[rowb * 64 + chb * 8];
            }
        }
        #pragma unroll
        for (int ks = 0; ks < 4; ks++)
            #pragma unroll
            for (int i = 0; i < 2; i++)
                #pragma unroll
                for (int j = 0; j < 2; j++)
                    acc[i][j] = __builtin_amdgcn_mfma_f32_32x32x16_bf16(af[ks][i], bfr[ks][j], acc[i][j], 0, 0, 0);
        __syncthreads();
    }

    #pragma unroll
    for (int i = 0; i < 2; i++)
        #pragma unroll
        for (int j = 0; j < 2; j++)
            #pragma unroll
            for (int r = 0; r < 16; r++) {
                int row = arow + wm * 64 + i * 32 + lh * 4 + (r & 3) + 8 * (r >> 2);
                int col = brow + wn * 64 + j * 32 + l31;
                C[(size_t)row * N + col] = acc[i][j][r];
            }
}

// ---------------------------------------------------------------------------
// RMSNorm + RoPE: fp32 [rows][rstride] (col-offset pre-applied) -> bf16
// [B][nh][S][128]. One wave per (row, head).
// ---------------------------------------------------------------------------
__global__ __launch_bounds__(256) void norm_rope(const float* __restrict__ X, int rstride,
                                                 const float* __restrict__ cosp,
                                                 const float* __restrict__ sinp,
                                                 const float* __restrict__ w,
                                                 unsigned short* __restrict__ Y, int nh) {
    const int wid  = blockIdx.x * 4 + (threadIdx.x >> 6);
    const int lane = threadIdx.x & 63;
    const int row  = wid / nh;
    const int h    = wid - row * nh;

    const float* xp = X + (size_t)row * rstride + h * 128;
    float x0 = xp[lane], x1 = xp[lane + 64];
    float ss = x0 * x0 + x1 * x1;
    #pragma unroll
    for (int off = 32; off; off >>= 1) ss += __shfl_xor(ss, off, 64);
    float r = rsqrtf(ss * (1.0f / 128.0f) + 1e-6f);
    float n0 = x0 * r * w[lane];
    float n1 = x1 * r * w[lane + 64];
    const float* cp = cosp + (size_t)row * 128;
    const float* sp = sinp + (size_t)row * 128;
    float y0 = n0 * cp[lane]      - n1 * sp[lane];
    float y1 = n1 * cp[lane + 64] + n0 * sp[lane + 64];
    const int b = row >> 10, s = row & 1023;
    unsigned short* yp = Y + (((size_t)(b * nh + h)) * 1024 + s) * 128;
    yp[lane]      = f2b(y0);
    yp[lane + 64] = f2b(y1);
}

// ---------------------------------------------------------------------------
// V transpose via LDS: fp32 V-region rows [b*1024+s][6144] (pointer
// pre-offset to col 5120) -> bf16 Vt[b][h][128][1024]. 64x64 tiles.
// ---------------------------------------------------------------------------
__global__ __launch_bounds__(256) void v_trans(const float* __restrict__ V,
                                               unsigned short* __restrict__ Vt) {
    __shared__ float T[64][65];
    const int tid = threadIdx.x;
    const int st = blockIdx.x >> 1, dt = blockIdx.x & 1;
    const int bh = blockIdx.y, b = bh >> 3, h = bh & 7;

    const int sl = tid >> 2, c0 = (tid & 3) * 16;
    const float* src = V + (size_t)(b * 1024 + st * 64 + sl) * 6144 + h * 128 + dt * 64 + c0;
    #pragma unroll
    for (int j = 0; j < 4; j++) {
        float4 v = *(const float4*)(src + j * 4);
        *(float4*)&T[sl][c0 + j * 4] = v;
    }
    __syncthreads();

    const int dgrp = tid >> 6, sl2 = tid & 63;
    unsigned short* dst = Vt + (size_t)bh * 131072 + st * 64 + sl2;
    #pragma unroll
    for (int jd = 0; jd < 16; jd++) {
        int dl = dgrp * 16 + jd;
        dst[(size_t)(dt * 64 + dl) * 1024] = f2b(T[sl2][dl]);
    }
}

// ---------------------------------------------------------------------------
// Flash attention (causal, GQA 4:1). Block = 64 Q rows (4 waves x 16 rows),
// processes q-tiles {qt, 15-qt} -> 9 k-tiles per block (balanced).
// ---------------------------------------------------------------------------
__global__ __launch_bounds__(256) void attn(const unsigned short* __restrict__ Qb,
                                            const unsigned short* __restrict__ Kb,
                                            const unsigned short* __restrict__ Vt,
                                            unsigned short* __restrict__ Ob) {
    __shared__ __align__(16) unsigned short Klds[128 * 128];
    __shared__ __align__(16) unsigned short Plds[4][16][136];

    const int tid  = threadIdx.x;
    const int w    = tid >> 6, lane = tid & 63;
    const int quad = lane >> 4, l15 = lane & 15;
    const int h = blockIdx.y, b = blockIdx.z, kvh = h >> 2;

    const unsigned short* Qp = Qb + ((size_t)(b * 32 + h))   * 131072;
    const unsigned short* Kp = Kb + ((size_t)(b * 8 + kvh))  * 131072;
    const unsigned short* Vp = Vt + ((size_t)(b * 8 + kvh))  * 131072;
    const float c2 = (float)(0.08838834764831845 * 1.4426950408889634); // D^-.5 * log2(e)

    for (int half = 0; half < 2; half++) {
        const int qt = half ? (15 - (int)blockIdx.x) : (int)blockIdx.x;
        const int q0 = qt * 64;
        const int qrow = q0 + w * 16 + l15;

        bf16x8 qf[4];
        #pragma unroll
        for (int ks = 0; ks < 4; ks++)
            qf[ks] = *(const bf16x8*)(Qp + (size_t)qrow * 128 + ks * 32 + quad * 8);

        float m_i[4], l_i[4];
        #pragma unroll
        for (int r = 0; r < 4; r++) { m_i[r] = -1e30f; l_i[r] = 0.0f; }
        f32x4 o[8] = {};

        const int ntiles = (qt >> 1) + 1;
        const int nfull  = (qt * 64 + 1) >> 7;   // tiles [0,nfull) need no mask

        for (int kt = 0; kt < ntiles; kt++) {
            __syncthreads();   // Klds readers of previous tile are done
            #pragma unroll
            for (int it = 0; it < 8; it++) {
                int slot = it * 4 + w;
                int ci = slot * 64 + lane;
                int r = ci >> 4, c = ci & 15;
                int g = (c & 8) | ((c ^ r) & 7);
                async16(Kp + (size_t)(kt * 128 + r) * 128 + g * 8, &Klds[slot * 512]);
            }
            __syncthreads();

            // S = Q @ K^T
            f32x4 sacc[8] = {};
            __builtin_amdgcn_s_setprio(1);
            #pragma unroll
            for (int ks = 0; ks < 4; ks++) {
                #pragma unroll
                for (int tn = 0; tn < 8; tn++) {
                    int row = tn * 16 + l15;
                    int ch  = ks * 4 + quad;
                    int chs = (ch & 8) | ((ch ^ row) & 7);
                    bf16x8 kf = *(const bf16x8*)&Klds[row * 128 + chs * 8];
                    sacc[tn] = __builtin_amdgcn_mfma_f32_16x16x32_bf16(qf[ks], kf, sacc[tn], 0, 0, 0);
                }
            }
            __builtin_amdgcn_s_setprio(0);

            const bool masked = (kt >= nfull);
            #pragma unroll
            for (int r = 0; r < 4; r++) {
                float sv[8];
                float rmax = -1e30f;
                if (masked) {
                    const int qg = q0 + w * 16 + quad * 4 + r;
                    #pragma unroll
                    for (int tn = 0; tn < 8; tn++) {
                        float v = sacc[tn][r];
                        int kg = kt * 128 + tn * 16 + l15;
                        if (kg > qg) v = -1e30f;
                        sv[tn] = v;
                        rmax = fmaxf(rmax, v);
                    }
                } else {
                    #pragma unroll
                    for (int tn = 0; tn < 8; tn++) {
                        sv[tn] = sacc[tn][r];
                        rmax = fmaxf(rmax, sv[tn]);
                    }
                }
                #pragma unroll
                for (int off = 8; off; off >>= 1) rmax = fmaxf(rmax, __shfl_xor(rmax, off, 16));
                float mnew  = fmaxf(m_i[r], rmax);
                float alpha = __builtin_amdgcn_exp2f((m_i[r] - mnew) * c2);
                float rsum  = 0.0f;
                #pragma unroll
                for (int tn = 0; tn < 8; tn++) {
                    float p = __builtin_amdgcn_exp2f((sv[tn] - mnew) * c2);
                    sv[tn] = p;
                    rsum += p;
                }
                #pragma unroll
                for (int off = 8; off; off >>= 1) rsum += __shfl_xor(rsum, off, 16);
                m_i[r] = mnew;
                l_i[r] = l_i[r] * alpha + rsum;
                #pragma unroll
                for (int td = 0; td < 8; td++) o[td][r] *= alpha;
                #pragma unroll
                for (int tn = 0; tn < 8; tn++)
                    Plds[w][quad * 4 + r][tn * 16 + l15] = f2b(sv[tn]);
            }

            // O += P @ V
            __builtin_amdgcn_s_setprio(1);
            #pragma unroll
            for (int ks = 0; ks < 4; ks++) {
                bf16x8 pf = *(const bf16x8*)&Plds[w][l15][ks * 32 + quad * 8];
                #pragma unroll
                for (int td = 0; td < 8; td++) {
                    bf16x8 vf = *(const bf16x8*)(Vp + (size_t)(td * 16 + l15) * 1024 + kt * 128 + ks * 32 + quad * 8);
                    o[td] = __builtin_amdgcn_mfma_f32_16x16x32_bf16(pf, vf, o[td], 0, 0, 0);
                }
            }
            __builtin_amdgcn_s_setprio(0);
        }

        #pragma unroll
        for (int r = 0; r < 4; r++) {
            float inv = 1.0f / l_i[r];
            const int qg = q0 + w * 16 + quad * 4 + r;
            unsigned short* op = Ob + ((size_t)(b * 1024 + qg)) * 4096 + h * 128;
            #pragma unroll
            for (int td = 0; td < 8; td++)
                op[td * 16 + l15] = f2b(o[td][r] * inv);
        }
    }
}

// ---------------------------------------------------------------------------
extern "C" void kernel_launch(void* const* d_in, const int* in_sizes, int n_in,
                              void* d_out, int out_size, void* d_ws, size_t ws_size,
                              hipStream_t stream) {
    const float* hid  = (const float*)d_in[0];
    const float* cosp = (const float*)d_in[1];
    const float* sinp = (const float*)d_in[2];
    const float* Wq   = (const float*)d_in[3];
    const float* Wk   = (const float*)d_in[4];
    const float* Wv   = (const float*)d_in[5];
    const float* Wo   = (const float*)d_in[6];
    const float* qw   = (const float*)d_in[7];
    const float* kw   = (const float*)d_in[8];
    float* out = (float*)d_out;

    // workspace carve (148 MB, aliased lifetimes)
    char* ws = (char*)d_ws;
    float* QKVf = (float*)ws;                               // [2048][6144] fp32 (50.3MB)
    unsigned short* Ob = (unsigned short*)ws;               // alias: QKVf dead before attn
    size_t off = (size_t)2048 * 6144 * 4;
    unsigned short* hidb  = (unsigned short*)(ws + off); off += (size_t)2048 * 4096 * 2;
    unsigned short* Wqkvb = (unsigned short*)(ws + off); off += (size_t)6144 * 4096 * 2;
    unsigned short* Wob   = (unsigned short*)(ws + off);
    unsigned short* Qb    = hidb;                            // alias: hidb dead after QKV
    unsigned short* Kb    = Wqkvb;                           // alias: Wqkvb dead after QKV
    unsigned short* Vt    = Wqkvb + (size_t)2048 * 1024;

    dim3 blk(256);
    // fp32 -> bf16 converts (single launch)
    cvt_all<<<24576, blk, 0, stream>>>(hid, Wq, Wk, Wv, Wo, hidb, Wqkvb, Wob);
    // fused QKV projection: [2048][6144] = hidb @ Wqkvb^T (256x192 tiles)
    gemm256_bt<<<dim3(32, 8), dim3(512), 0, stream>>>(hidb, Wqkvb, QKVf, 4096, 6144);
    // norm + rope + layout
    norm_rope<<<16384, blk, 0, stream>>>(QKVf,        6144, cosp, sinp, qw, Qb, 32);
    norm_rope<<<4096,  blk, 0, stream>>>(QKVf + 4096, 6144, cosp, sinp, kw, Kb, 8);
    v_trans<<<dim3(32, 16), blk, 0, stream>>>(QKVf + 5120, Vt);
    // attention
    attn<<<dim3(8, 32, 2), blk, 0, stream>>>(Qb, Kb, Vt, Ob);
    // output projection
    gemm_bt_bf16<<<dim3(32, 16), blk, 0, stream>>>(Ob, Wob, out, 4096, 4096);
}

// Round 4
// 503.774 us; speedup vs baseline: 1.0287x; 1.0192x over previous
//
#include <hip/hip_runtime.h>

// ---------------------------------------------------------------------------
// Qwen3 attention block: B=2 S=1024 H=4096 NH=32 NKV=8 D=128
// Round 8: barrier-ectomy on gemm256_bt. R0-R2 all landed at 116-117us with
// 8 barriers/K-tile lockstep; audit shows 7 of 8 enforce nothing (A triple-
// buffered, B frags read once/tile at boundary => >=1 full tile slack between
// last read and re-stage). New K-loop: ONE vmcnt(4)+s_barrier per K-tile,
// free-running phases with counted lgkm {4,4,4,10}, reg pipeline rA..rD +
// B ping-pong unchanged from verified R2 ledger. K/N hardcoded (4096/6144)
// to kill the 18% VALU address overhead.
// ---------------------------------------------------------------------------

typedef float  f32x4   __attribute__((ext_vector_type(4)));
typedef float  f32x16  __attribute__((ext_vector_type(16)));
typedef __bf16 bf16x8  __attribute__((ext_vector_type(8)));
typedef unsigned short u16x8 __attribute__((ext_vector_type(8)));

__device__ __forceinline__ unsigned short f2b(float f) {
    union { float f; unsigned int u; } x;
    x.f = f;
    unsigned int u = x.u;
    unsigned int r = u + 0x7fffu + ((u >> 16) & 1u);   // RNE
    return (unsigned short)(r >> 16);
}

// async global->LDS, 16B per lane. LDS dst = wave-uniform base + lane*16.
__device__ __forceinline__ void async16(const unsigned short* g, unsigned short* l) {
    __builtin_amdgcn_global_load_lds(
        (const __attribute__((address_space(1))) void*)g,
        (__attribute__((address_space(3))) void*)l, 16, 0, 0);
}

// ---------------------------------------------------------------------------
// fp32 -> bf16 convert, all five regions in one launch. 8 elems/thread.
// ---------------------------------------------------------------------------
__global__ __launch_bounds__(256) void cvt_all(const float* __restrict__ hsrc,
                                               const float* __restrict__ wq,
                                               const float* __restrict__ wk,
                                               const float* __restrict__ wv,
                                               const float* __restrict__ wo,
                                               unsigned short* __restrict__ hidb,
                                               unsigned short* __restrict__ wqkvb,
                                               unsigned short* __restrict__ wob) {
    int i = blockIdx.x * 256 + threadIdx.x;
    if (i >= 6291456) return;
    const float* s; unsigned short* d; int j;
    if (i < 1048576)      { s = hsrc; d = hidb;             j = i; }
    else if (i < 3145728) { s = wq;   d = wqkvb;            j = i - 1048576; }
    else if (i < 3670016) { s = wk;   d = wqkvb + 16777216; j = i - 3145728; }
    else if (i < 4194304) { s = wv;   d = wqkvb + 20971520; j = i - 3670016; }
    else                  { s = wo;   d = wob;              j = i - 4194304; }
    const float4* s4 = (const float4*)s + (size_t)j * 2;
    float4 a = s4[0], b = s4[1];
    u16x8 o;
    o[0] = f2b(a.x); o[1] = f2b(a.y); o[2] = f2b(a.z); o[3] = f2b(a.w);
    o[4] = f2b(b.x); o[5] = f2b(b.y); o[6] = f2b(b.z); o[7] = f2b(b.w);
    *((u16x8*)d + j) = o;
}

// ---------------------------------------------------------------------------
// Deep-pipelined GEMM (K=4096, N=6144 hardcoded): C = A @ W^T, fp32 out.
// Tile 256x192, BK=64, 512 threads = 8 waves (2M x 4N), wave = 128x48 via
// 8x3 grid of mfma_f32_16x16x32_bf16. Grid 32x8 = 256 blocks = 1/CU.
// LDS: A[3 bufs][256x64], B[2 bufs][192x64] = 144KB.
// K-loop: free-running (NO intra-tile barriers). Per tile t:
//   q0: rd q1->rB; stage B(t+1)x3;      lgkm(4);  MFMA q0(rA)
//   q1: rd q2->rC; stage A(t+2)s0,s1;   lgkm(4);  MFMA q1(rB)
//   q2: rd q3->rD; stage A(t+2)s2,s3;   lgkm(4);  MFMA q2(rC)
//   boundary: vmcnt(4) [proves A(t+1)+B(t+1), keeps A(t+2)]; s_barrier;
//             rd B(t+1)->BN + q0(t+1)->rA; lgkm(10); MFMA q3(rD)
// Safety (1 barrier/tile): stage B(t+1) overwrites buf last LDS-read at
// boundary t-2 (barrier t-1 between); stage A(t+2) overwrites buf last read
// mid-tile t-1 (barrier t-1 between); boundary reads after barrier t which
// follows own-wave vmcnt(4). lgkm counted per-wave, DS in-order, no SMEM.
// ---------------------------------------------------------------------------
__global__ __launch_bounds__(512, 2) void gemm256_bt(const unsigned short* __restrict__ A,
                                                     const unsigned short* __restrict__ W,
                                                     float* __restrict__ C) {
    constexpr int K = 4096, N = 6144;
    __shared__ __align__(16) unsigned short Ab[3][256 * 64];
    __shared__ __align__(16) unsigned short Bb[2][192 * 64];

    const int tid  = threadIdx.x;
    const int wave = tid >> 6, lane = tid & 63;
    const int wm   = wave >> 2, wn = wave & 3;
    const int l15  = lane & 15, h = lane >> 4;
    const int cx0  = (h ^ (l15 & 7)) << 3;              // frag read chunk (shorts)
    const int cx1  = cx0 ^ 32;                          // k + 32
    const int stgrow = wave * 8 + (lane >> 3);          // row within 64-row sweep
    const int stgcol = ((lane & 7) ^ (lane >> 3)) << 3; // pre-swizzled global chunk
    const int aRow0 = blockIdx.y * 256;
    const int bRow0 = blockIdx.x * 192;
    const int NT = K >> 6;

#define STAGE_A(t, s, bi) async16(A + (size_t)(aRow0 + (s)*64 + stgrow) * K + (t)*64 + stgcol, \
                                  &Ab[bi][(s)*4096 + wave*512])
#define STAGE_B(t, s, bi) async16(W + (size_t)(bRow0 + (s)*64 + stgrow) * K + (t)*64 + stgcol, \
                                  &Bb[bi][(s)*4096 + wave*512])
#define RD_AQ(dst, buf, q) do { \
    _Pragma("unroll") \
    for (int mi = 0; mi < 2; mi++) { \
        const unsigned short* ap_ = (buf) + (wm * 128 + (q) * 32 + mi * 16 + l15) * 64; \
        dst[mi][0] = *(const bf16x8*)(ap_ + cx0); \
        dst[mi][1] = *(const bf16x8*)(ap_ + cx1); \
    } } while (0)
#define RD_B(dst, buf) do { \
    _Pragma("unroll") \
    for (int nf = 0; nf < 3; nf++) { \
        const unsigned short* bp_ = (buf) + (wn * 48 + nf * 16 + l15) * 64; \
        dst[nf][0] = *(const bf16x8*)(bp_ + cx0); \
        dst[nf][1] = *(const bf16x8*)(bp_ + cx1); \
    } } while (0)
#define MFMA_Q(q, AR, BR) do { \
    _Pragma("unroll") \
    for (int mi = 0; mi < 2; mi++) \
    _Pragma("unroll") \
    for (int nf = 0; nf < 3; nf++) { \
        acc[(q)*2+mi][nf] = __builtin_amdgcn_mfma_f32_16x16x32_bf16(AR[mi][0], BR[nf][0], acc[(q)*2+mi][nf], 0, 0, 0); \
        acc[(q)*2+mi][nf] = __builtin_amdgcn_mfma_f32_16x16x32_bf16(AR[mi][1], BR[nf][1], acc[(q)*2+mi][nf], 0, 0, 0); \
    } } while (0)
#define SB()      __builtin_amdgcn_sched_barrier(0)
#define BARRIER() __builtin_amdgcn_s_barrier()
#define PRIO1()   __builtin_amdgcn_s_setprio(1)
#define PRIO0()   __builtin_amdgcn_s_setprio(0)
#define LGKM(n)   asm volatile("s_waitcnt lgkmcnt(" #n ")" ::: "memory")

#define TILE(T, BC, BN_) do { \
    const int t_ = (T); \
    const unsigned short* Ab_ = Ab[t_ % 3]; \
    const int rb1 = (t_ & 1) ^ 1, ra2 = (t_ + 2) % 3; \
    const bool sb = (t_ + 1 < NT), sa = (t_ + 2 < NT); \
    /* ---- q0 */ \
    RD_AQ(rB, Ab_, 1); \
    if (sb) { STAGE_B(t_ + 1, 0, rb1); STAGE_B(t_ + 1, 1, rb1); STAGE_B(t_ + 1, 2, rb1); } \
    SB(); LGKM(4); SB(); \
    PRIO1(); MFMA_Q(0, rA, BC); PRIO0(); SB(); \
    /* ---- q1 */ \
    RD_AQ(rC, Ab_, 2); \
    if (sa) { STAGE_A(t_ + 2, 0, ra2); STAGE_A(t_ + 2, 1, ra2); } \
    SB(); LGKM(4); SB(); \
    PRIO1(); MFMA_Q(1, rB, BC); PRIO0(); SB(); \
    /* ---- q2 */ \
    RD_AQ(rD, Ab_, 3); \
    if (sa) { STAGE_A(t_ + 2, 2, ra2); STAGE_A(t_ + 2, 3, ra2); } \
    SB(); LGKM(4); SB(); \
    PRIO1(); MFMA_Q(2, rC, BC); PRIO0(); SB(); \
    /* ---- boundary: one vmcnt + one barrier per K-tile */ \
    if (sa) asm volatile("s_waitcnt vmcnt(4)" ::: "memory"); \
    else    asm volatile("s_waitcnt vmcnt(0)" ::: "memory"); \
    SB(); BARRIER(); SB(); \
    if (sb) { RD_B(BN_, Bb[(t_ + 1) & 1]); RD_AQ(rA, Ab[(t_ + 1) % 3], 0); } \
    SB(); \
    if (sb) { LGKM(10); } else { LGKM(0); } \
    SB(); \
    PRIO1(); MFMA_Q(3, rD, BC); PRIO0(); SB(); \
} while (0)

    f32x4 acc[8][3] = {};
    bf16x8 rA[2][2], rB[2][2], rC[2][2], rD[2][2];
    bf16x8 bc[3][2], bn[3][2];

    // prologue: B(0)->Bb0, A(0)->Ab0, A(1)->Ab1; leave A(1) in flight
    STAGE_B(0, 0, 0); STAGE_B(0, 1, 0); STAGE_B(0, 2, 0);
    STAGE_A(0, 0, 0); STAGE_A(0, 1, 0); STAGE_A(0, 2, 0); STAGE_A(0, 3, 0);
    STAGE_A(1, 0, 1); STAGE_A(1, 1, 1); STAGE_A(1, 2, 1); STAGE_A(1, 3, 1);
    asm volatile("s_waitcnt vmcnt(4)" ::: "memory");
    SB(); BARRIER(); SB();
    // pre-read tile 0: B frags + q0 (10 lgkm outstanding entering the loop)
    RD_B(bc, Bb[0]);
    RD_AQ(rA, Ab[0], 0);
    SB();

    for (int t = 0; t < NT; t += 2) {
        TILE(t,     bc, bn);
        TILE(t + 1, bn, bc);
    }

    // epilogue: C/D 16x16 frag layout col=l&15, row=(l>>4)*4+r
    #pragma unroll
    for (int mf = 0; mf < 8; mf++)
        #pragma unroll
        for (int nf = 0; nf < 3; nf++)
            #pragma unroll
            for (int r = 0; r < 4; r++) {
                int row = aRow0 + wm * 128 + mf * 16 + h * 4 + r;
                int col = bRow0 + wn * 48 + nf * 16 + l15;
                C[(size_t)row * N + col] = acc[mf][nf][r];
            }
#undef STAGE_A
#undef STAGE_B
#undef RD_AQ
#undef RD_B
#undef MFMA_Q
#undef SB
#undef BARRIER
#undef PRIO1
#undef PRIO0
#undef LGKM
#undef TILE
}

// ---------------------------------------------------------------------------
// GEMM: C[M,N] fp32 = A[M,K]bf16 @ W[N,K]bf16^T. 128x128 tile, BK=64.
// (kept for the output projection: N=4096 not divisible by 192)
// ---------------------------------------------------------------------------
__global__ __launch_bounds__(256) void gemm_bt_bf16(const unsigned short* __restrict__ A,
                                                    const unsigned short* __restrict__ W,
                                                    float* __restrict__ C,
                                                    int K, int N) {
    __shared__ __align__(16) unsigned short As[128 * 64];
    __shared__ __align__(16) unsigned short Bs[128 * 64];

    const int tid  = threadIdx.x;
    const int wave = tid >> 6, lane = tid & 63;
    const int wm   = wave >> 1, wn = wave & 1;
    const int l31  = lane & 31, lh = lane >> 5;
    const int arow = blockIdx.y * 128, brow = blockIdx.x * 128;

    int rr[4], gc[4], slot[4];
    #pragma unroll
    for (int it = 0; it < 4; it++) {
        slot[it] = it * 4 + wave;
        int ci = slot[it] * 64 + lane;
        rr[it] = ci >> 3;
        int c  = ci & 7;
        gc[it] = c ^ (rr[it] & 7);
    }

    f32x16 acc[2][2] = {};

    for (int k0 = 0; k0 < K; k0 += 64) {
        #pragma unroll
        for (int it = 0; it < 4; it++) {
            async16(A + (size_t)(arow + rr[it]) * K + k0 + gc[it] * 8, &As[slot[it] * 512]);
            async16(W + (size_t)(brow + rr[it]) * K + k0 + gc[it] * 8, &Bs[slot[it] * 512]);
        }
        __syncthreads();

        bf16x8 af[4][2], bfr[4][2];
        #pragma unroll
        for (int ks = 0; ks < 4; ks++) {
            #pragma unroll
            for (int i = 0; i < 2; i++) {
                int rowa = wm * 64 + i * 32 + l31;
                int ch   = (ks * 2 + lh) ^ (rowa & 7);
                af[ks][i]  = *(const bf16x8*)&As[rowa * 64 + ch * 8];
                int rowb = wn * 64 + i * 32 + l31;
                int chb  = (ks * 2 + lh) ^ (rowb & 7);
                bfr[ks][i] = *(const bf16x8*)&Bs[rowb * 64 + chb * 8];
            }
        }
        #pragma unroll
        for (int ks = 0; ks < 4; ks++)
            #pragma unroll
            for (int i = 0; i < 2; i++)
                #pragma unroll
                for (int j = 0; j < 2; j++)
                    acc[i][j] = __builtin_amdgcn_mfma_f32_32x32x16_bf16(af[ks][i], bfr[ks][j], acc[i][j], 0, 0, 0);
        __syncthreads();
    }

    #pragma unroll
    for (int i = 0; i < 2; i++)
        #pragma unroll
        for (int j = 0; j < 2; j++)
            #pragma unroll
            for (int r = 0; r < 16; r++) {
                int row = arow + wm * 64 + i * 32 + lh * 4 + (r & 3) + 8 * (r >> 2);
                int col = brow + wn * 64 + j * 32 + l31;
                C[(size_t)row * N + col] = acc[i][j][r];
            }
}

// ---------------------------------------------------------------------------
// RMSNorm + RoPE: fp32 [rows][rstride] (col-offset pre-applied) -> bf16
// [B][nh][S][128]. One wave per (row, head).
// ---------------------------------------------------------------------------
__global__ __launch_bounds__(256) void norm_rope(const float* __restrict__ X, int rstride,
                                                 const float* __restrict__ cosp,
                                                 const float* __restrict__ sinp,
                                                 const float* __restrict__ w,
                                                 unsigned short* __restrict__ Y, int nh) {
    const int wid  = blockIdx.x * 4 + (threadIdx.x >> 6);
    const int lane = threadIdx.x & 63;
    const int row  = wid / nh;
    const int h    = wid - row * nh;

    const float* xp = X + (size_t)row * rstride + h * 128;
    float x0 = xp[lane], x1 = xp[lane + 64];
    float ss = x0 * x0 + x1 * x1;
    #pragma unroll
    for (int off = 32; off; off >>= 1) ss += __shfl_xor(ss, off, 64);
    float r = rsqrtf(ss * (1.0f / 128.0f) + 1e-6f);
    float n0 = x0 * r * w[lane];
    float n1 = x1 * r * w[lane + 64];
    const float* cp = cosp + (size_t)row * 128;
    const float* sp = sinp + (size_t)row * 128;
    float y0 = n0 * cp[lane]      - n1 * sp[lane];
    float y1 = n1 * cp[lane + 64] + n0 * sp[lane + 64];
    const int b = row >> 10, s = row & 1023;
    unsigned short* yp = Y + (((size_t)(b * nh + h)) * 1024 + s) * 128;
    yp[lane]      = f2b(y0);
    yp[lane + 64] = f2b(y1);
}

// ---------------------------------------------------------------------------
// V transpose via LDS: fp32 V-region rows [b*1024+s][6144] (pointer
// pre-offset to col 5120) -> bf16 Vt[b][h][128][1024]. 64x64 tiles.
// ---------------------------------------------------------------------------
__global__ __launch_bounds__(256) void v_trans(const float* __restrict__ V,
                                               unsigned short* __restrict__ Vt) {
    __shared__ float T[64][65];
    const int tid = threadIdx.x;
    const int st = blockIdx.x >> 1, dt = blockIdx.x & 1;
    const int bh = blockIdx.y, b = bh >> 3, h = bh & 7;

    const int sl = tid >> 2, c0 = (tid & 3) * 16;
    const float* src = V + (size_t)(b * 1024 + st * 64 + sl) * 6144 + h * 128 + dt * 64 + c0;
    #pragma unroll
    for (int j = 0; j < 4; j++) {
        float4 v = *(const float4*)(src + j * 4);
        *(float4*)&T[sl][c0 + j * 4] = v;
    }
    __syncthreads();

    const int dgrp = tid >> 6, sl2 = tid & 63;
    unsigned short* dst = Vt + (size_t)bh * 131072 + st * 64 + sl2;
    #pragma unroll
    for (int jd = 0; jd < 16; jd++) {
        int dl = dgrp * 16 + jd;
        dst[(size_t)(dt * 64 + dl) * 1024] = f2b(T[sl2][dl]);
    }
}

// ---------------------------------------------------------------------------
// Flash attention (causal, GQA 4:1). Block = 64 Q rows (4 waves x 16 rows),
// processes q-tiles {qt, 15-qt} -> 9 k-tiles per block (balanced).
// ---------------------------------------------------------------------------
__global__ __launch_bounds__(256) void attn(const unsigned short* __restrict__ Qb,
                                            const unsigned short* __restrict__ Kb,
                                            const unsigned short* __restrict__ Vt,
                                            unsigned short* __restrict__ Ob) {
    __shared__ __align__(16) unsigned short Klds[128 * 128];
    __shared__ __align__(16) unsigned short Plds[4][16][136];

    const int tid  = threadIdx.x;
    const int w    = tid >> 6, lane = tid & 63;
    const int quad = lane >> 4, l15 = lane & 15;
    const int h = blockIdx.y, b = blockIdx.z, kvh = h >> 2;

    const unsigned short* Qp = Qb + ((size_t)(b * 32 + h))   * 131072;
    const unsigned short* Kp = Kb + ((size_t)(b * 8 + kvh))  * 131072;
    const unsigned short* Vp = Vt + ((size_t)(b * 8 + kvh))  * 131072;
    const float c2 = (float)(0.08838834764831845 * 1.4426950408889634); // D^-.5 * log2(e)

    for (int half = 0; half < 2; half++) {
        const int qt = half ? (15 - (int)blockIdx.x) : (int)blockIdx.x;
        const int q0 = qt * 64;
        const int qrow = q0 + w * 16 + l15;

        bf16x8 qf[4];
        #pragma unroll
        for (int ks = 0; ks < 4; ks++)
            qf[ks] = *(const bf16x8*)(Qp + (size_t)qrow * 128 + ks * 32 + quad * 8);

        float m_i[4], l_i[4];
        #pragma unroll
        for (int r = 0; r < 4; r++) { m_i[r] = -1e30f; l_i[r] = 0.0f; }
        f32x4 o[8] = {};

        const int ntiles = (qt >> 1) + 1;
        const int nfull  = (qt * 64 + 1) >> 7;   // tiles [0,nfull) need no mask

        for (int kt = 0; kt < ntiles; kt++) {
            __syncthreads();   // Klds readers of previous tile are done
            #pragma unroll
            for (int it = 0; it < 8; it++) {
                int slot = it * 4 + w;
                int ci = slot * 64 + lane;
                int r = ci >> 4, c = ci & 15;
                int g = (c & 8) | ((c ^ r) & 7);
                async16(Kp + (size_t)(kt * 128 + r) * 128 + g * 8, &Klds[slot * 512]);
            }
            __syncthreads();

            // S = Q @ K^T
            f32x4 sacc[8] = {};
            __builtin_amdgcn_s_setprio(1);
            #pragma unroll
            for (int ks = 0; ks < 4; ks++) {
                #pragma unroll
                for (int tn = 0; tn < 8; tn++) {
                    int row = tn * 16 + l15;
                    int ch  = ks * 4 + quad;
                    int chs = (ch & 8) | ((ch ^ row) & 7);
                    bf16x8 kf = *(const bf16x8*)&Klds[row * 128 + chs * 8];
                    sacc[tn] = __builtin_amdgcn_mfma_f32_16x16x32_bf16(qf[ks], kf, sacc[tn], 0, 0, 0);
                }
            }
            __builtin_amdgcn_s_setprio(0);

            const bool masked = (kt >= nfull);
            #pragma unroll
            for (int r = 0; r < 4; r++) {
                float sv[8];
                float rmax = -1e30f;
                if (masked) {
                    const int qg = q0 + w * 16 + quad * 4 + r;
                    #pragma unroll
                    for (int tn = 0; tn < 8; tn++) {
                        float v = sacc[tn][r];
                        int kg = kt * 128 + tn * 16 + l15;
                        if (kg > qg) v = -1e30f;
                        sv[tn] = v;
                        rmax = fmaxf(rmax, v);
                    }
                } else {
                    #pragma unroll
                    for (int tn = 0; tn < 8; tn++) {
                        sv[tn] = sacc[tn][r];
                        rmax = fmaxf(rmax, sv[tn]);
                    }
                }
                #pragma unroll
                for (int off = 8; off; off >>= 1) rmax = fmaxf(rmax, __shfl_xor(rmax, off, 16));
                float mnew  = fmaxf(m_i[r], rmax);
                float alpha = __builtin_amdgcn_exp2f((m_i[r] - mnew) * c2);
                float rsum  = 0.0f;
                #pragma unroll
                for (int tn = 0; tn < 8; tn++) {
                    float p = __builtin_amdgcn_exp2f((sv[tn] - mnew) * c2);
                    sv[tn] = p;
                    rsum += p;
                }
                #pragma unroll
                for (int off = 8; off; off >>= 1) rsum += __shfl_xor(rsum, off, 16);
                m_i[r] = mnew;
                l_i[r] = l_i[r] * alpha + rsum;
                #pragma unroll
                for (int td = 0; td < 8; td++) o[td][r] *= alpha;
                #pragma unroll
                for (int tn = 0; tn < 8; tn++)
                    Plds[w][quad * 4 + r][tn * 16 + l15] = f2b(sv[tn]);
            }

            // O += P @ V
            __builtin_amdgcn_s_setprio(1);
            #pragma unroll
            for (int ks = 0; ks < 4; ks++) {
                bf16x8 pf = *(const bf16x8*)&Plds[w][l15][ks * 32 + quad * 8];
                #pragma unroll
                for (int td = 0; td < 8; td++) {
                    bf16x8 vf = *(const bf16x8*)(Vp + (size_t)(td * 16 + l15) * 1024 + kt * 128 + ks * 32 + quad * 8);
                    o[td] = __builtin_amdgcn_mfma_f32_16x16x32_bf16(pf, vf, o[td], 0, 0, 0);
                }
            }
            __builtin_amdgcn_s_setprio(0);
        }

        #pragma unroll
        for (int r = 0; r < 4; r++) {
            float inv = 1.0f / l_i[r];
            const int qg = q0 + w * 16 + quad * 4 + r;
            unsigned short* op = Ob + ((size_t)(b * 1024 + qg)) * 4096 + h * 128;
            #pragma unroll
            for (int td = 0; td < 8; td++)
                op[td * 16 + l15] = f2b(o[td][r] * inv);
        }
    }
}

// ---------------------------------------------------------------------------
extern "C" void kernel_launch(void* const* d_in, const int* in_sizes, int n_in,
                              void* d_out, int out_size, void* d_ws, size_t ws_size,
                              hipStream_t stream) {
    const float* hid  = (const float*)d_in[0];
    const float* cosp = (const float*)d_in[1];
    const float* sinp = (const float*)d_in[2];
    const float* Wq   = (const float*)d_in[3];
    const float* Wk   = (const float*)d_in[4];
    const float* Wv   = (const float*)d_in[5];
    const float* Wo   = (const float*)d_in[6];
    const float* qw   = (const float*)d_in[7];
    const float* kw   = (const float*)d_in[8];
    float* out = (float*)d_out;

    // workspace carve (148 MB, aliased lifetimes)
    char* ws = (char*)d_ws;
    float* QKVf = (float*)ws;                               // [2048][6144] fp32 (50.3MB)
    unsigned short* Ob = (unsigned short*)ws;               // alias: QKVf dead before attn
    size_t off = (size_t)2048 * 6144 * 4;
    unsigned short* hidb  = (unsigned short*)(ws + off); off += (size_t)2048 * 4096 * 2;
    unsigned short* Wqkvb = (unsigned short*)(ws + off); off += (size_t)6144 * 4096 * 2;
    unsigned short* Wob   = (unsigned short*)(ws + off);
    unsigned short* Qb    = hidb;                            // alias: hidb dead after QKV
    unsigned short* Kb    = Wqkvb;                           // alias: Wqkvb dead after QKV
    unsigned short* Vt    = Wqkvb + (size_t)2048 * 1024;

    dim3 blk(256);
    // fp32 -> bf16 converts (single launch)
    cvt_all<<<24576, blk, 0, stream>>>(hid, Wq, Wk, Wv, Wo, hidb, Wqkvb, Wob);
    // fused QKV projection: [2048][6144] = hidb @ Wqkvb^T (256x192 tiles)
    gemm256_bt<<<dim3(32, 8), dim3(512), 0, stream>>>(hidb, Wqkvb, QKVf);
    // norm + rope + layout
    norm_rope<<<16384, blk, 0, stream>>>(QKVf,        6144, cosp, sinp, qw, Qb, 32);
    norm_rope<<<4096,  blk, 0, stream>>>(QKVf + 4096, 6144, cosp, sinp, kw, Kb, 8);
    v_trans<<<dim3(32, 16), blk, 0, stream>>>(QKVf + 5120, Vt);
    // attention
    attn<<<dim3(8, 32, 2), blk, 0, stream>>>(Qb, Kb, Vt, Ob);
    // output projection
    gemm_bt_bf16<<<dim3(32, 16), blk, 0, stream>>>(Ob, Wob, out, 4096, 4096);
}